// Round 10
// baseline (227.106 us; speedup 1.0000x reference)
//
#include <hip/hip_runtime.h>
#include <stdint.h>

#define NB 32
#define NP 32768
#define NO 32
#define THRESH 0.35f
#define NT1 64          // x-tiles per batch (512 priors each)

typedef unsigned long long u64;
typedef unsigned int u32;

// fast IoU from prior corners + truth corners. Phase-1 additions and the selector's
// delta-subtractions must cancel bit-exactly, so BOTH use this helper.
__device__ __forceinline__ float iou_corners(float px1, float py1, float px2, float py2, float ab,
                                             float tx1, float ty1, float tx2, float ty2, float aa)
{
#pragma clang fp contract(off)
    float iw = fminf(tx2, px2) - fmaxf(tx1, px1);
    float ih = fminf(ty2, py2) - fmaxf(ty1, py1);
    iw = fmaxf(iw, 0.f); ih = fmaxf(ih, 0.f);
    float inter = iw * ih;
    return __fdividef(inter, aa + ab - inter);
}

__device__ __forceinline__ float smooth_l1_sum(float4 ld, float4 pr, float4 tt)
{
#pragma clang fp contract(off)
    float g0 = __fdividef((tt.x + tt.z) * 0.5f - pr.x, 0.1f * pr.z);
    float g1 = __fdividef((tt.y + tt.w) * 0.5f - pr.y, 0.1f * pr.w);
    float g2 = __logf(__fdividef(tt.z - tt.x, pr.z)) * 5.0f;
    float g3 = __logf(__fdividef(tt.w - tt.y, pr.w)) * 5.0f;
    float d0 = ld.x - g0, d1 = ld.y - g1, d2 = ld.z - g2, d3 = ld.w - g3;
    float a0 = fabsf(d0), a1 = fabsf(d1), a2 = fabsf(d2), a3 = fabsf(d3);
    return (a0 < 1.f ? 0.5f * d0 * d0 : a0 - 0.5f)
         + (a1 < 1.f ? 0.5f * d1 * d1 : a1 - 0.5f)
         + (a2 < 1.f ? 0.5f * d2 * d2 : a2 - 0.5f)
         + (a3 < 1.f ? 0.5f * d3 * d3 : a3 - 0.5f);
}

__device__ __forceinline__ float lse2(float c0, float c1)
{
#pragma clang fp contract(off)
    float mm = fmaxf(c0, c1), mn = fminf(c0, c1);
    return mm + __logf(1.f + __expf(mn - mm));
}

// ---------------- Fused kernel: per-tile losses + last-block-per-batch select ----------
// grid (64 tiles, 32 batches) x 256 threads; 2 consecutive priors/thread.
// Phase 1 = R9 kern1 (staggered o: spreads keys[] LDS atomics over 32 addrs —
// load-bearing, see R5 regression 44->95us with wave-uniform o).
// The LAST tile-block to finish a batch (batch_done ticket) becomes that batch's
// selector: fence-acquire, fix deltas, then 4-pass streaming radix-select from L2/L3.
// Cross-XCD coherence: producers __threadfence() (L2 writeback) before the ticket
// atomicAdd; selector __threadfence() after (L2 invalidate) before reading mine.
// hist[256][17] keeps LDS <= ~20KB so 8 blocks/CU stays (launch_bounds(256,8)).
#define HCOL 17
__global__ __launch_bounds__(256, 8) void kern_fused(
        const float* __restrict__ loc, const float* __restrict__ conf,
        const float* __restrict__ priors, const float* __restrict__ targets,
        float* __restrict__ mine, u64* __restrict__ bpk,
        int* __restrict__ batch_done,
        float* __restrict__ batch_sl1, float* __restrict__ batch_cep, int* __restrict__ batch_np,
        float* __restrict__ sl_tot, float* __restrict__ c_tot,
        int* __restrict__ np_tot, int* __restrict__ done_cnt,
        float* __restrict__ out)
{
#pragma clang fp contract(off)
    __shared__ __align__(16) float4 tbc[NO];   // truth corners (persist into select phase)
    __shared__ float ta[NO], tlab[NO];
    __shared__ u64 keys[NO];
    __shared__ float rs0[4], rs1[4];
    __shared__ int rc[4];
    __shared__ int hist[256 * HCOL];           // 17 KB, selector only
    __shared__ int total[256];
    __shared__ u32 pp[NO];
    __shared__ float rs[4];
    __shared__ int rc2[4];
    __shared__ float sh_sl1, sh_cep;
    __shared__ int sh_np, sh_k, sh_kk, sh_sel;
    __shared__ u32 sh_prefix;

    const int b = blockIdx.y, x = blockIdx.x, tid = threadIdx.x;
    const int lane = tid & 63, wave = tid >> 6;
    if (tid < NO * 5) {
        int o = tid / 5, c = tid % 5;
        float v = targets[b * NO * 5 + tid];
        if (c < 4) ((float*)&tbc[o])[c] = v; else tlab[o] = v;
    }
    if (tid < NO) keys[tid] = 0ull;
    __syncthreads();
    if (tid < NO) {
        float4 t = tbc[tid];
        ta[tid] = (t.z - t.x) * (t.w - t.y);
    }
    __syncthreads();

    // ================= phase 1: this tile's IoUs + pre-fix losses =================
    const int p0 = x * 512 + tid * 2;
    float4 pr[2];
    float px1[2], py1[2], px2[2], py2[2], ab[2];
#pragma unroll
    for (int j = 0; j < 2; ++j) {
        pr[j] = ((const float4*)priors)[p0 + j];
        px1[j] = pr[j].x - pr[j].z * 0.5f;
        py1[j] = pr[j].y - pr[j].w * 0.5f;
        px2[j] = pr[j].x + pr[j].z * 0.5f;
        py2[j] = pr[j].y + pr[j].w * 0.5f;
        ab[j]  = pr[j].z * pr[j].w;
    }
    // per-prior best truth as packed u64: (iou_bits << 6) | (63 - o)
    u64 bk[2] = {0ull, 0ull};
    const int lane_o = tid & 31;
    for (int it = 0; it < NO; ++it) {
        const int o = (it + lane_o) & 31;
        float4 tt = tbc[o];
        float aa = ta[o];
        float iou2[2];
#pragma unroll
        for (int j = 0; j < 2; ++j) {
            float iou = iou_corners(px1[j], py1[j], px2[j], py2[j], ab[j],
                                    tt.x, tt.y, tt.z, tt.w, aa);
            iou2[j] = iou;
            u64 ko = ((u64)__float_as_uint(iou) << 6) | (u64)(63 - o);
            bk[j] = bk[j] > ko ? bk[j] : ko;
        }
        float vm = fmaxf(iou2[0], iou2[1]);
        u64 cur = keys[o];
        if (__float_as_uint(vm) > (u32)(cur >> 32)) {
            float bi = iou2[1]; int bp = p0 + 1;
            if (iou2[0] >= bi) { bi = iou2[0]; bp = p0; }
            atomicMax(&keys[o], ((u64)__float_as_uint(bi) << 32) | (u64)(~(u32)bp));
        }
    }

    const size_t gbase = (size_t)b * NP + p0;
    float4 cf = ((const float4*)conf)[gbase >> 1];
    float c0[2] = {cf.x, cf.z};
    float c1[2] = {cf.y, cf.w};
    float2 mout;
    float s_sl1 = 0.f, s_cep = 0.f;
    int np = 0;
#pragma unroll
    for (int j = 0; j < 2; ++j) {
        u32 vb = (u32)(bk[j] >> 6);
        float bv = __uint_as_float(vb);
        int o = 63 - (int)(bk[j] & 63);
        int cfv = (bv < THRESH) ? 0 : ((int)tlab[o] + 1);
        bool pos = cfv > 0;
        float4 ld = ((const float4*)loc)[gbase + j];
        float sl1 = smooth_l1_sum(ld, pr[j], tbc[o]);
        float ce = lse2(c0[j], c1[j]) - ((cfv == 0) ? c0[j] : c1[j]);
        if (pos) { s_sl1 += sl1; s_cep += ce; np++; }
        ((float*)&mout)[j] = pos ? 0.f : ce;
    }
    ((float2*)mine)[gbase >> 1] = mout;

#pragma unroll
    for (int m = 32; m; m >>= 1) {
        s_sl1 += __shfl_xor(s_sl1, m, 64);
        s_cep += __shfl_xor(s_cep, m, 64);
        np    += __shfl_xor(np, m, 64);
    }
    if (lane == 0) { rs0[wave] = s_sl1; rs1[wave] = s_cep; rc[wave] = np; }
    if (tid < NO) atomicMax(&bpk[b * NO + tid], keys[tid]);   // global per-truth best
    __syncthreads();                 // all stores (mine) + LDS reduces complete
    if (tid == 0) {
        float t0 = 0.f, t1 = 0.f; int t2 = 0;
        for (int i = 0; i < 4; ++i) { t0 += rs0[i]; t1 += rs1[i]; t2 += rc[i]; }
        atomicAdd(&batch_sl1[b], t0);
        atomicAdd(&batch_cep[b], t1);
        atomicAdd(&batch_np[b], t2);
        __threadfence();             // release: mine[] + partials visible device-wide
        int done = atomicAdd(&batch_done[b], 1);
        sh_sel = (done == NT1 - 1) ? 1 : 0;
    }
    __syncthreads();
    if (!sh_sel) return;             // non-last blocks exit; last block = selector

    // ================= select phase (one block per batch) =================
    __threadfence();                 // acquire: invalidate local caches for cross-XCD reads
    __syncthreads();
    if (tid < NO) {
        u64 key = bpk[b * NO + tid]; // written only by atomics; fence above makes it fresh
        pp[tid] = (key >> 32) ? ~(u32)key : 0u;   // all-zero row => argmax = 0
    }
    __syncthreads();
    if (tid < NO) {
        const int o = tid;
        const u32 p = pp[o];
        float dsl1 = 0.f, dcep = 0.f; int dnp = 0;
        bool last = true;
        for (int o2 = o + 1; o2 < NO; ++o2)
            if (pp[o2] == p) { last = false; break; }   // later o overwrites same prior
        if (last) {
            float4 prr = ((const float4*)priors)[p];
            float qx1 = prr.x - prr.z * 0.5f, qy1 = prr.y - prr.w * 0.5f;
            float qx2 = prr.x + prr.z * 0.5f, qy2 = prr.y + prr.w * 0.5f;
            float qab = prr.z * prr.w;
            float bv = -1.f; int bo_ = 0;    // pre-fix best truth (first-max)
            for (int o2 = 0; o2 < NO; ++o2) {
                float4 t2 = tbc[o2];
                float aa2 = (t2.z - t2.x) * (t2.w - t2.y);
                float i2 = iou_corners(qx1, qy1, qx2, qy2, qab, t2.x, t2.y, t2.z, t2.w, aa2);
                if (i2 > bv) { bv = i2; bo_ = o2; }
            }
            int cf_pre = (bv < THRESH) ? 0 : ((int)tlab[bo_] + 1);
            size_t gp = (size_t)b * NP + p;
            float4 ld = ((const float4*)loc)[gp];
            float2 c = ((const float2*)conf)[gp];
            float lse = lse2(c.x, c.y);
            int cf_new = (int)tlab[o] + 1;               // forced positive
            dsl1 = smooth_l1_sum(ld, prr, tbc[o]);
            dcep = lse - ((cf_new == 0) ? c.x : c.y);
            dnp = 1;
            if (cf_pre > 0) {                            // remove pre-fix contribution
                dsl1 -= smooth_l1_sum(ld, prr, tbc[bo_]);
                dcep -= lse - ((cf_pre == 0) ? c.x : c.y);
                dnp = 0;
            }
            mine[gp] = 0.f;            // forced prior is pos; streaming below sees this
        }
#pragma unroll
        for (int m = 16; m; m >>= 1) {
            dsl1 += __shfl_xor(dsl1, m, 32);
            dcep += __shfl_xor(dcep, m, 32);
            dnp  += __shfl_xor(dnp, m, 32);
        }
        if (o == 0) {
            float a = atomicAdd(&batch_sl1[b], 0.f) + dsl1;
            float d = atomicAdd(&batch_cep[b], 0.f) + dcep;
            int   n = atomicAdd(&batch_np[b], 0)   + dnp;
            sh_sl1 = a; sh_cep = d; sh_np = n;
            sh_k = min(7 * n, NP - 1); sh_kk = sh_k; sh_prefix = 0u;
        }
    }
    __syncthreads();                  // also orders mine[gp]=0 stores before streaming
    const int k = sh_k;
    float topk = 0.f;
    const float* mb = mine + (size_t)b * NP;
    const int cl = lane & (HCOL - 2); // column = lane&15 (HCOL=17)
    if (k > 0) {
        for (int pass = 0; pass < 4; ++pass) {
#pragma unroll
            for (int i = 0; i < HCOL; ++i) hist[i * 256 + tid] = 0;   // clear (any layout)
            __syncthreads();
            const int shift = 24 - 8 * pass;
            const u32 pfx = sh_prefix;
            for (int j = 0; j < 32; ++j) {              // stream 128 KB from L2/L3
                float4 t4 = ((const float4*)mb)[j * 256 + tid];
#pragma unroll
                for (int c = 0; c < 4; ++c) {
                    u32 kb = __float_as_uint(((const float*)&t4)[c]);
                    if ((u32)(((u64)kb) >> (shift + 8)) == pfx)   // 64-bit shift: ok at 32
                        atomicAdd(&hist[((kb >> shift) & 255) * HCOL + cl], 1);
                }
            }
            __syncthreads();
            {   // reduce 16 cols/bin: thread t sums bin t (rows stride 17 = conflict-free)
                int s = 0;
                const int base = tid * HCOL;
#pragma unroll
                for (int i = 0; i < HCOL - 1; ++i) s += hist[base + i];
                total[tid] = s;
            }
            __syncthreads();
            if (tid < 64) {                  // suffix-scan select over 256 bins
                int4 h4 = ((const int4*)total)[tid];
                int s3 = h4.w, s2 = h4.z + s3, s1 = h4.y + s2, s0 = h4.x + s1;
                int acc = s0;
#pragma unroll
                for (int off = 1; off < 64; off <<= 1) {
                    int u = __shfl_down(acc, off, 64);
                    if (tid + off < 64) acc += u;
                }
                int excl = acc - s0;
                int kk = sh_kk;
                int cand = -1, nkk = 0;
                if (excl + s3 >= kk)      { cand = 4 * tid + 3; nkk = kk - excl; }
                else if (excl + s2 >= kk) { cand = 4 * tid + 2; nkk = kk - excl - s3; }
                else if (excl + s1 >= kk) { cand = 4 * tid + 1; nkk = kk - excl - s2; }
                else if (excl + s0 >= kk) { cand = 4 * tid + 0; nkk = kk - excl - s1; }
                int cmax = cand;
#pragma unroll
                for (int off = 1; off < 64; off <<= 1) cmax = max(cmax, __shfl_xor(cmax, off, 64));
                if (cand >= 0 && cand == cmax) {
                    sh_prefix = (pfx << 8) | (u32)(cand & 255);
                    sh_kk = nkk;
                }
            }
            __syncthreads();
        }
        const u32 T = sh_prefix;                // exact k-th largest key
        const float tval = __uint_as_float(T);
        float s = 0.f; int c2 = 0;
        for (int j = 0; j < 32; ++j) {          // final stream: sum of keys > T
            float4 t4 = ((const float4*)mb)[j * 256 + tid];
#pragma unroll
            for (int c = 0; c < 4; ++c) {
                float vv = ((const float*)&t4)[c];
                if (__float_as_uint(vv) > T) { s += vv; c2++; }
            }
        }
#pragma unroll
        for (int m = 32; m; m >>= 1) {
            s  += __shfl_xor(s, m, 64);
            c2 += __shfl_xor(c2, m, 64);
        }
        if (lane == 0) { rs[wave] = s; rc2[wave] = c2; }
        __syncthreads();
        if (tid == 0) {
            float st = 0.f; int ct = 0;
            for (int i = 0; i < 4; ++i) { st += rs[i]; ct += rc2[i]; }
            topk = st + (float)(k - ct) * tval; // ties at T fill remaining slots
        }
    }
    if (tid == 0) {                            // accumulate + last-batch finalize
        atomicAdd(sl_tot, sh_sl1);
        atomicAdd(c_tot, sh_cep + topk);
        atomicAdd(np_tot, sh_np);
        __threadfence();
        int d = atomicAdd(done_cnt, 1);
        if (d == NB - 1) {
            float sl = atomicAdd(sl_tot, 0.f);
            float cc = atomicAdd(c_tot, 0.f);
            int   nn = atomicAdd(np_tot, 0);
            float N = fmaxf((float)nn, 1.f);
            out[0] = sl / N;
            out[1] = cc / N;
        }
    }
}

extern "C" void kernel_launch(void* const* d_in, const int* in_sizes, int n_in,
                              void* d_out, int out_size, void* d_ws, size_t ws_size,
                              hipStream_t stream) {
    const float* loc     = (const float*)d_in[0];   // (B,P,4)
    const float* conf    = (const float*)d_in[1];   // (B,P,2)
    const float* priors  = (const float*)d_in[2];   // (P,4)
    const float* targets = (const float*)d_in[3];   // (B,O,5)
    float* out = (float*)d_out;

    char* ws = (char*)d_ws;
    u64*   bpk        = (u64*)ws;                      // 8192 B, zeroed below
    int*   batch_done = (int*)(ws + 8192);             // 128 B
    float* batch_sl1  = (float*)(ws + 8320);           // 128 B
    float* batch_cep  = (float*)(ws + 8448);           // 128 B
    int*   batch_np   = (int*)(ws + 8576);             // 128 B
    float* sl_tot     = (float*)(ws + 8704);
    float* c_tot      = (float*)(ws + 8708);
    int*   np_tot     = (int*)(ws + 8712);
    int*   done_cnt   = (int*)(ws + 8716);             // header ends at 8720
    float* mine       = (float*)(ws + 16384);          // 4 MB, fully written by phase 1

    hipMemsetAsync(ws, 0, 8720, stream);
    dim3 g(NT1, NB);
    kern_fused<<<g, 256, 0, stream>>>(loc, conf, priors, targets, mine, bpk,
                                      batch_done, batch_sl1, batch_cep, batch_np,
                                      sl_tot, c_tot, np_tot, done_cnt, out);
}

// Round 11
// 130.792 us; speedup vs baseline: 1.7364x; 1.7364x over previous
//
#include <hip/hip_runtime.h>
#include <stdint.h>

#define NB 32
#define NP 32768
#define NO 32
#define THRESH 0.35f
#define NT1 64          // kern1 x-tiles (512 priors each)
#define H1COL 17        // kern1 pass-0 histogram columns

typedef unsigned long long u64;
typedef unsigned int u32;

// fast IoU from prior corners + truth corners. kern1's additions and kern3's
// delta-subtractions must cancel bit-exactly, so BOTH use this helper.
__device__ __forceinline__ float iou_corners(float px1, float py1, float px2, float py2, float ab,
                                             float tx1, float ty1, float tx2, float ty2, float aa)
{
#pragma clang fp contract(off)
    float iw = fminf(tx2, px2) - fmaxf(tx1, px1);
    float ih = fminf(ty2, py2) - fmaxf(ty1, py1);
    iw = fmaxf(iw, 0.f); ih = fmaxf(ih, 0.f);
    float inter = iw * ih;
    return __fdividef(inter, aa + ab - inter);
}

__device__ __forceinline__ float smooth_l1_sum(float4 ld, float4 pr, float4 tt)
{
#pragma clang fp contract(off)
    float g0 = __fdividef((tt.x + tt.z) * 0.5f - pr.x, 0.1f * pr.z);
    float g1 = __fdividef((tt.y + tt.w) * 0.5f - pr.y, 0.1f * pr.w);
    float g2 = __logf(__fdividef(tt.z - tt.x, pr.z)) * 5.0f;
    float g3 = __logf(__fdividef(tt.w - tt.y, pr.w)) * 5.0f;
    float d0 = ld.x - g0, d1 = ld.y - g1, d2 = ld.z - g2, d3 = ld.w - g3;
    float a0 = fabsf(d0), a1 = fabsf(d1), a2 = fabsf(d2), a3 = fabsf(d3);
    return (a0 < 1.f ? 0.5f * d0 * d0 : a0 - 0.5f)
         + (a1 < 1.f ? 0.5f * d1 * d1 : a1 - 0.5f)
         + (a2 < 1.f ? 0.5f * d2 * d2 : a2 - 0.5f)
         + (a3 < 1.f ? 0.5f * d3 * d3 : a3 - 0.5f);
}

__device__ __forceinline__ float lse2(float c0, float c1)
{
#pragma clang fp contract(off)
    float mm = fmaxf(c0, c1), mn = fminf(c0, c1);
    return mm + __logf(1.f + __expf(mn - mm));
}

// ---------------- K1: IoU + per-prior best + PRE-FIX losses + mine + pass-0 hist -------
// grid (64 tiles, 32 batches) x 256 threads; 2 consecutive priors/thread.
// 2048 blocks -> 8 blocks/CU -> 32 waves/CU (LDS ~18.5KB, VGPR ~32: both permit 8).
// o STAGGERED per lane — load-bearing (R5: wave-uniform o => same-address DS atomic
// serialization, kern1 44->95us). bpk atomicMax only AFTER __syncthreads (R10 latent
// race: keys[] still being updated by other threads otherwise).
__global__ __launch_bounds__(256) void kern1(
        const float* __restrict__ loc, const float* __restrict__ conf,
        const float* __restrict__ priors, const float* __restrict__ targets,
        float* __restrict__ mine, u64* __restrict__ bpk, int* __restrict__ hist256g,
        float* __restrict__ batch_sl1, float* __restrict__ batch_cep, int* __restrict__ batch_np)
{
#pragma clang fp contract(off)
    __shared__ __align__(16) float4 tbc[NO];
    __shared__ float ta[NO], tlab[NO];
    __shared__ u64 keys[NO];
    __shared__ int h1[256 * H1COL];            // 17.4 KB pass-0 histogram
    __shared__ float rs0[4], rs1[4];
    __shared__ int rc[4];
    const int b = blockIdx.y, x = blockIdx.x, tid = threadIdx.x;
    if (tid < NO * 5) {
        int o = tid / 5, c = tid % 5;
        float v = targets[b * NO * 5 + tid];
        if (c < 4) ((float*)&tbc[o])[c] = v; else tlab[o] = v;
    }
    if (tid < NO) keys[tid] = 0ull;
#pragma unroll
    for (int i = 0; i < H1COL; ++i) h1[i * 256 + tid] = 0;
    __syncthreads();
    if (tid < NO) {
        float4 t = tbc[tid];
        ta[tid] = (t.z - t.x) * (t.w - t.y);
    }
    __syncthreads();

    const int p0 = x * 512 + tid * 2;
    float4 pr[2];
    float px1[2], py1[2], px2[2], py2[2], ab[2];
#pragma unroll
    for (int j = 0; j < 2; ++j) {
        pr[j] = ((const float4*)priors)[p0 + j];
        px1[j] = pr[j].x - pr[j].z * 0.5f;
        py1[j] = pr[j].y - pr[j].w * 0.5f;
        px2[j] = pr[j].x + pr[j].z * 0.5f;
        py2[j] = pr[j].y + pr[j].w * 0.5f;
        ab[j]  = pr[j].z * pr[j].w;
    }
    // per-prior best truth as packed u64: (iou_bits << 6) | (63 - o)
    u64 bk[2] = {0ull, 0ull};
    const int lane_o = tid & 31;   // stagger (see note above)
    for (int it = 0; it < NO; ++it) {
        const int o = (it + lane_o) & 31;
        float4 tt = tbc[o];
        float aa = ta[o];
        float iou2[2];
#pragma unroll
        for (int j = 0; j < 2; ++j) {
            float iou = iou_corners(px1[j], py1[j], px2[j], py2[j], ab[j],
                                    tt.x, tt.y, tt.z, tt.w, aa);
            iou2[j] = iou;
            u64 ko = ((u64)__float_as_uint(iou) << 6) | (u64)(63 - o);
            bk[j] = bk[j] > ko ? bk[j] : ko;
        }
        float vm = fmaxf(iou2[0], iou2[1]);
        u64 cur = keys[o];
        if (__float_as_uint(vm) > (u32)(cur >> 32)) {
            float bi = iou2[1]; int bp = p0 + 1;
            if (iou2[0] >= bi) { bi = iou2[0]; bp = p0; }
            atomicMax(&keys[o], ((u64)__float_as_uint(bi) << 32) | (u64)(~(u32)bp));
        }
    }

    // ---- pre-fix losses straight from registers ----
    const size_t gbase = (size_t)b * NP + p0;
    float4 cf = ((const float4*)conf)[gbase >> 1];
    float c0[2] = {cf.x, cf.z};
    float c1[2] = {cf.y, cf.w};
    float2 mout;
    float s_sl1 = 0.f, s_cep = 0.f;
    int np = 0;
#pragma unroll
    for (int j = 0; j < 2; ++j) {
        u32 vb = (u32)(bk[j] >> 6);
        float bv = __uint_as_float(vb);
        int o = 63 - (int)(bk[j] & 63);
        int cfv = (bv < THRESH) ? 0 : ((int)tlab[o] + 1);
        bool pos = cfv > 0;
        float4 ld = ((const float4*)loc)[gbase + j];
        float sl1 = smooth_l1_sum(ld, pr[j], tbc[o]);
        float ce = lse2(c0[j], c1[j]) - ((cfv == 0) ? c0[j] : c1[j]);
        if (pos) { s_sl1 += sl1; s_cep += ce; np++; }
        ((float*)&mout)[j] = pos ? 0.f : ce;
    }
    ((float2*)mine)[gbase >> 1] = mout;
    // pass-0 histogram (pre-fix values); col=tid&15: <=4-way same-address (1.58x, m136)
    const int col = tid & 15;
    atomicAdd(&h1[(__float_as_uint(mout.x) >> 24) * H1COL + col], 1);
    atomicAdd(&h1[(__float_as_uint(mout.y) >> 24) * H1COL + col], 1);

#pragma unroll
    for (int m = 32; m; m >>= 1) {
        s_sl1 += __shfl_xor(s_sl1, m, 64);
        s_cep += __shfl_xor(s_cep, m, 64);
        np    += __shfl_xor(np, m, 64);
    }
    int lane = tid & 63, w = tid >> 6;
    if (lane == 0) { rs0[w] = s_sl1; rs1[w] = s_cep; rc[w] = np; }
    __syncthreads();               // keys, h1, rs all final
    if (tid < NO) atomicMax(&bpk[b * NO + tid], keys[tid]);
    {   // flush pass-0 histogram: thread t owns bin t
        int s = 0;
        const int base = tid * H1COL;
#pragma unroll
        for (int i = 0; i < 16; ++i) s += h1[base + i];
        if (s) atomicAdd(&hist256g[b * 256 + tid], s);
    }
    if (tid == 0) {
        float t0 = 0.f, t1 = 0.f; int t2 = 0;
        for (int i = 0; i < 4; ++i) { t0 += rs0[i]; t1 += rs1[i]; t2 += rc[i]; }
        atomicAdd(&batch_sl1[b], t0);
        atomicAdd(&batch_cep[b], t1);
        atomicAdd(&batch_np[b], t2);
    }
}

// ---------------- K3: fix + deltas + radix passes 1-3 + finalize ------------------------
// one block per batch, 1024 threads. Pass 0 comes precomputed from kern1 (hist256g);
// kern3 applies <=32 fix corrections to it, then runs passes 1-3 from register-resident
// v[32] with the proven 256x33 column-per-lane histogram (R7: all-bank coverage).
#define HCOL 33
__global__ __launch_bounds__(1024) void kern3(
        const float* __restrict__ loc, const float* __restrict__ conf,
        const float* __restrict__ priors, const float* __restrict__ targets,
        const u64* __restrict__ bpk, const float* __restrict__ mine,
        const int* __restrict__ hist256g,
        const float* __restrict__ batch_sl1, const float* __restrict__ batch_cep,
        const int* __restrict__ batch_np,
        float* __restrict__ sl_tot, float* __restrict__ c_tot,
        int* __restrict__ np_tot, int* __restrict__ done_cnt,
        float* __restrict__ out)
{
#pragma clang fp contract(off)
    const int b = blockIdx.x, tid = threadIdx.x;
    const int wave = tid >> 6, lane = tid & 63;
    const int cl = lane & 31;
    __shared__ __align__(16) float4 tbc[NO];
    __shared__ float tlab[NO], tas[NO];
    __shared__ u32 pp[NO];
    __shared__ u32 flags[1024];
    __shared__ int hist[256 * HCOL];            // 33 KB
    __shared__ int total[256];
    __shared__ float rs[16];
    __shared__ int rc2[16];
    __shared__ float sh_sl1, sh_cep;
    __shared__ int sh_np, sh_k, sh_kk;
    __shared__ u32 sh_prefix;

    if (tid < NO * 5) {
        int o = tid / 5, c = tid % 5;
        float v = targets[b * NO * 5 + tid];
        if (c < 4) ((float*)&tbc[o])[c] = v; else tlab[o] = v;
    }
    flags[tid] = 0u;
    if (tid < 256) total[tid] = hist256g[b * 256 + tid];   // kern1's pass-0 bins
    const float* mb = mine + (size_t)b * NP;
    float v[32];
#pragma unroll
    for (int q = 0; q < 8; ++q) {
        float4 t4 = ((const float4*)mb)[q * 1024 + tid];
        v[4 * q] = t4.x; v[4 * q + 1] = t4.y; v[4 * q + 2] = t4.z; v[4 * q + 3] = t4.w;
    }
    if (tid < NO) {
        float4 t = tbc[tid];     // tbc written by this warp region? guarded below by sync
        // (tbc[tid] is loaded by threads tid<160 above; tid<32 subset reads its own row
        //  only after __syncthreads below — so defer tas to after barrier)
    }
    __syncthreads();
    if (tid < NO) {
        float4 t = tbc[tid];
        tas[tid] = (t.z - t.x) * (t.w - t.y);
        u64 key = bpk[b * NO + tid];
        pp[tid] = (key >> 32) ? ~(u32)key : 0u;   // all-zero row => argmax = 0
    }
    __syncthreads();
    if (tid < NO) {
        const int o = tid;
        const u32 p = pp[o];
        float dsl1 = 0.f, dcep = 0.f; int dnp = 0;
        bool last = true;
        for (int o2 = o + 1; o2 < NO; ++o2)
            if (pp[o2] == p) { last = false; break; }   // later o overwrites same prior
        if (last) {
            float4 prr = ((const float4*)priors)[p];
            float qx1 = prr.x - prr.z * 0.5f, qy1 = prr.y - prr.w * 0.5f;
            float qx2 = prr.x + prr.z * 0.5f, qy2 = prr.y + prr.w * 0.5f;
            float qab = prr.z * prr.w;
            float bv = -1.f; int bo_ = 0;    // pre-fix best truth (first-max)
            for (int o2 = 0; o2 < NO; ++o2) {
                float4 t2 = tbc[o2];
                float i2 = iou_corners(qx1, qy1, qx2, qy2, qab, t2.x, t2.y, t2.z, t2.w, tas[o2]);
                if (i2 > bv) { bv = i2; bo_ = o2; }
            }
            int cf_pre = (bv < THRESH) ? 0 : ((int)tlab[bo_] + 1);
            size_t gp = (size_t)b * NP + p;
            float4 ld = ((const float4*)loc)[gp];
            float2 c = ((const float2*)conf)[gp];
            float lse = lse2(c.x, c.y);
            int cf_new = (int)tlab[o] + 1;               // forced positive
            dsl1 = smooth_l1_sum(ld, prr, tbc[o]);
            dcep = lse - ((cf_new == 0) ? c.x : c.y);
            dnp = 1;
            if (cf_pre > 0) {                            // remove pre-fix contribution
                dsl1 -= smooth_l1_sum(ld, prr, tbc[bo_]);
                dcep -= lse - ((cf_pre == 0) ? c.x : c.y);
                dnp = 0;
            }
            // pass-0 correction: old value leaves its bin, 0.0 enters bin 0
            float oldv = mb[p];
            atomicSub(&total[__float_as_uint(oldv) >> 24], 1);
            atomicAdd(&total[0], 1);
            atomicOr(&flags[p >> 5], 1u << (p & 31));
        }
#pragma unroll
        for (int m = 16; m; m >>= 1) {
            dsl1 += __shfl_xor(dsl1, m, 32);
            dcep += __shfl_xor(dcep, m, 32);
            dnp  += __shfl_xor(dnp, m, 32);
        }
        if (o == 0) {
            float a = batch_sl1[b] + dsl1;
            float d = batch_cep[b] + dcep;
            int   n = batch_np[b]  + dnp;
            sh_sl1 = a; sh_cep = d; sh_np = n;
            sh_k = min(7 * n, NP - 1); sh_kk = sh_k; sh_prefix = 0u;
        }
    }
    __syncthreads();
    // zero forced priors in-register (they become pos => mine 0)
#pragma unroll
    for (int q = 0; q < 8; ++q) {
        u32 word = flags[q * 128 + (tid >> 3)];
#pragma unroll
        for (int c = 0; c < 4; ++c)
            if ((word >> (((tid & 7) << 2) + c)) & 1u) v[4 * q + c] = 0.f;
    }
    const int k = sh_k;
    float topk = 0.f;
    if (k > 0) {
        for (int pass = 0; pass < 4; ++pass) {
            if (pass > 0) {                      // pass 0's totals came from kern1
                for (int i = tid; i < 256 * HCOL; i += 1024) hist[i] = 0;
                __syncthreads();
                const int shift = 24 - 8 * pass;
                const u32 pfx = sh_prefix;
#pragma unroll 8
                for (int j = 0; j < 32; ++j) {
                    u32 kb = __float_as_uint(v[j]);
                    if ((u32)(((u64)kb) >> (shift + 8)) == pfx)   // 64-bit shift: ok at 32
                        atomicAdd(&hist[((kb >> shift) & 255) * HCOL + cl], 1);
                }
                __syncthreads();
                if (tid < 512) {   // reduce 32 cols/bin: 2 threads per bin, 16 each
                    int bin = tid >> 1;
                    const int base = bin * HCOL + (tid & 1) * 16;
                    int s = 0;
#pragma unroll
                    for (int i = 0; i < 16; ++i) s += hist[base + i];
                    s += __shfl_xor(s, 1, 64);
                    if ((tid & 1) == 0) total[bin] = s;
                }
                __syncthreads();
            }
            if (tid < 64) {                  // suffix-scan select over 256 bins
                int4 h4 = ((const int4*)total)[tid];
                int s3 = h4.w, s2 = h4.z + s3, s1 = h4.y + s2, s0 = h4.x + s1;
                int acc = s0;
#pragma unroll
                for (int off = 1; off < 64; off <<= 1) {
                    int u = __shfl_down(acc, off, 64);
                    if (tid + off < 64) acc += u;
                }
                int excl = acc - s0;
                int kk = sh_kk;
                int cand = -1, nkk = 0;
                if (excl + s3 >= kk)      { cand = 4 * tid + 3; nkk = kk - excl; }
                else if (excl + s2 >= kk) { cand = 4 * tid + 2; nkk = kk - excl - s3; }
                else if (excl + s1 >= kk) { cand = 4 * tid + 1; nkk = kk - excl - s2; }
                else if (excl + s0 >= kk) { cand = 4 * tid + 0; nkk = kk - excl - s1; }
                int cmax = cand;
#pragma unroll
                for (int off = 1; off < 64; off <<= 1) cmax = max(cmax, __shfl_xor(cmax, off, 64));
                if (cand >= 0 && cand == cmax) {
                    sh_prefix = (sh_prefix << 8) | (u32)(cand & 255);
                    sh_kk = nkk;
                }
            }
            __syncthreads();
        }
        const u32 T = sh_prefix;                // exact k-th largest key
        const float tval = __uint_as_float(T);
        float s = 0.f; int c2 = 0;
#pragma unroll
        for (int j = 0; j < 32; ++j) {
            if (__float_as_uint(v[j]) > T) { s += v[j]; c2++; }
        }
#pragma unroll
        for (int m = 32; m; m >>= 1) {
            s  += __shfl_xor(s, m, 64);
            c2 += __shfl_xor(c2, m, 64);
        }
        if (lane == 0) { rs[wave] = s; rc2[wave] = c2; }
        __syncthreads();
        if (tid == 0) {
            float st = 0.f; int ct = 0;
            for (int i = 0; i < 16; ++i) { st += rs[i]; ct += rc2[i]; }
            topk = st + (float)(k - ct) * tval; // ties at T fill remaining slots
        }
    }
    if (tid == 0) {                            // accumulate + last-block finalize
        atomicAdd(sl_tot, sh_sl1);
        atomicAdd(c_tot, sh_cep + topk);
        atomicAdd(np_tot, sh_np);
        __threadfence();
        int d = atomicAdd(done_cnt, 1);
        if (d == NB - 1) {
            float sl = atomicAdd(sl_tot, 0.f);
            float cc = atomicAdd(c_tot, 0.f);
            int   nn = atomicAdd(np_tot, 0);
            float N = fmaxf((float)nn, 1.f);
            out[0] = sl / N;
            out[1] = cc / N;
        }
    }
}

extern "C" void kernel_launch(void* const* d_in, const int* in_sizes, int n_in,
                              void* d_out, int out_size, void* d_ws, size_t ws_size,
                              hipStream_t stream) {
    const float* loc     = (const float*)d_in[0];   // (B,P,4)
    const float* conf    = (const float*)d_in[1];   // (B,P,2)
    const float* priors  = (const float*)d_in[2];   // (P,4)
    const float* targets = (const float*)d_in[3];   // (B,O,5)
    float* out = (float*)d_out;

    char* ws = (char*)d_ws;
    u64*   bpk       = (u64*)ws;                     // 8 KB  [b][o] global best-prior keys
    int*   hist256g  = (int*)(ws + 8192);            // 32 KB [b][256] pass-0 bins
    float* batch_sl1 = (float*)(ws + 40960);         // 128 B
    float* batch_cep = (float*)(ws + 41088);         // 128 B
    int*   batch_np  = (int*)(ws + 41216);           // 128 B
    float* sl_tot    = (float*)(ws + 41344);
    float* c_tot     = (float*)(ws + 41348);
    int*   np_tot    = (int*)(ws + 41352);
    int*   done_cnt  = (int*)(ws + 41356);           // header ends 41360
    float* mine      = (float*)(ws + 65536);         // 4 MB, fully written by kern1

    hipMemsetAsync(ws, 0, 41360, stream);
    dim3 g1(NT1, NB);
    kern1<<<g1, 256, 0, stream>>>(loc, conf, priors, targets, mine, bpk, hist256g,
                                  batch_sl1, batch_cep, batch_np);
    kern3<<<NB, 1024, 0, stream>>>(loc, conf, priors, targets, bpk, mine, hist256g,
                                   batch_sl1, batch_cep, batch_np,
                                   sl_tot, c_tot, np_tot, done_cnt, out);
}

// Round 12
// 127.538 us; speedup vs baseline: 1.7807x; 1.0255x over previous
//
#include <hip/hip_runtime.h>
#include <stdint.h>

#define NB 32
#define NP 32768
#define NO 32
#define THRESH 0.35f
#define NT1 64          // kern1 x-tiles (512 priors each)

typedef unsigned long long u64;
typedef unsigned int u32;

// fast IoU from prior corners + truth corners. kern1's additions and kern3's
// delta-subtractions must cancel bit-exactly, so BOTH use this helper.
__device__ __forceinline__ float iou_corners(float px1, float py1, float px2, float py2, float ab,
                                             float tx1, float ty1, float tx2, float ty2, float aa)
{
#pragma clang fp contract(off)
    float iw = fminf(tx2, px2) - fmaxf(tx1, px1);
    float ih = fminf(ty2, py2) - fmaxf(ty1, py1);
    iw = fmaxf(iw, 0.f); ih = fmaxf(ih, 0.f);
    float inter = iw * ih;
    return __fdividef(inter, aa + ab - inter);
}

__device__ __forceinline__ float smooth_l1_sum(float4 ld, float4 pr, float4 tt)
{
#pragma clang fp contract(off)
    float g0 = __fdividef((tt.x + tt.z) * 0.5f - pr.x, 0.1f * pr.z);
    float g1 = __fdividef((tt.y + tt.w) * 0.5f - pr.y, 0.1f * pr.w);
    float g2 = __logf(__fdividef(tt.z - tt.x, pr.z)) * 5.0f;
    float g3 = __logf(__fdividef(tt.w - tt.y, pr.w)) * 5.0f;
    float d0 = ld.x - g0, d1 = ld.y - g1, d2 = ld.z - g2, d3 = ld.w - g3;
    float a0 = fabsf(d0), a1 = fabsf(d1), a2 = fabsf(d2), a3 = fabsf(d3);
    return (a0 < 1.f ? 0.5f * d0 * d0 : a0 - 0.5f)
         + (a1 < 1.f ? 0.5f * d1 * d1 : a1 - 0.5f)
         + (a2 < 1.f ? 0.5f * d2 * d2 : a2 - 0.5f)
         + (a3 < 1.f ? 0.5f * d3 * d3 : a3 - 0.5f);
}

__device__ __forceinline__ float lse2(float c0, float c1)
{
#pragma clang fp contract(off)
    float mm = fmaxf(c0, c1), mn = fminf(c0, c1);
    return mm + __logf(1.f + __expf(mn - mm));
}

// ---------------- K1: IoU + per-prior best + PRE-FIX losses + mine ---------------------
// grid (64 tiles, 32 batches) x 256 threads; 2 consecutive priors/thread.
// 2048 blocks -> 8 blocks/CU -> 32 waves/CU. o STAGGERED per lane — load-bearing
// (R5: wave-uniform o => same-address DS atomic serialization, kern1 44->95us).
// keys published via global atomicMax AFTER __syncthreads (R10 race lesson).
__global__ __launch_bounds__(256) void kern1(
        const float* __restrict__ loc, const float* __restrict__ conf,
        const float* __restrict__ priors, const float* __restrict__ targets,
        float* __restrict__ mine, u64* __restrict__ bpk,
        float* __restrict__ part_sl1, float* __restrict__ part_cep, int* __restrict__ part_np)
{
#pragma clang fp contract(off)
    __shared__ __align__(16) float4 tbc[NO];
    __shared__ float ta[NO], tlab[NO];
    __shared__ u64 keys[NO];
    __shared__ float rs0[4], rs1[4];
    __shared__ int rc[4];
    const int b = blockIdx.y, x = blockIdx.x, tid = threadIdx.x;
    if (tid < NO * 5) {
        int o = tid / 5, c = tid % 5;
        float v = targets[b * NO * 5 + tid];
        if (c < 4) ((float*)&tbc[o])[c] = v; else tlab[o] = v;
    }
    if (tid < NO) keys[tid] = 0ull;
    __syncthreads();
    if (tid < NO) {
        float4 t = tbc[tid];
        ta[tid] = (t.z - t.x) * (t.w - t.y);
    }
    __syncthreads();

    const int p0 = x * 512 + tid * 2;
    float4 pr[2];
    float px1[2], py1[2], px2[2], py2[2], ab[2];
#pragma unroll
    for (int j = 0; j < 2; ++j) {
        pr[j] = ((const float4*)priors)[p0 + j];
        px1[j] = pr[j].x - pr[j].z * 0.5f;
        py1[j] = pr[j].y - pr[j].w * 0.5f;
        px2[j] = pr[j].x + pr[j].z * 0.5f;
        py2[j] = pr[j].y + pr[j].w * 0.5f;
        ab[j]  = pr[j].z * pr[j].w;
    }
    // per-prior best truth as packed u64: (iou_bits << 6) | (63 - o)
    u64 bk[2] = {0ull, 0ull};
    const int lane_o = tid & 31;   // stagger (see note above)
    for (int it = 0; it < NO; ++it) {
        const int o = (it + lane_o) & 31;
        float4 tt = tbc[o];
        float aa = ta[o];
        float iou2[2];
#pragma unroll
        for (int j = 0; j < 2; ++j) {
            float iou = iou_corners(px1[j], py1[j], px2[j], py2[j], ab[j],
                                    tt.x, tt.y, tt.z, tt.w, aa);
            iou2[j] = iou;
            u64 ko = ((u64)__float_as_uint(iou) << 6) | (u64)(63 - o);
            bk[j] = bk[j] > ko ? bk[j] : ko;
        }
        float vm = fmaxf(iou2[0], iou2[1]);
        u64 cur = keys[o];
        if (__float_as_uint(vm) > (u32)(cur >> 32)) {
            float bi = iou2[1]; int bp = p0 + 1;
            if (iou2[0] >= bi) { bi = iou2[0]; bp = p0; }
            atomicMax(&keys[o], ((u64)__float_as_uint(bi) << 32) | (u64)(~(u32)bp));
        }
    }

    // ---- pre-fix losses straight from registers ----
    const size_t gbase = (size_t)b * NP + p0;
    float4 cf = ((const float4*)conf)[gbase >> 1];
    float c0[2] = {cf.x, cf.z};
    float c1[2] = {cf.y, cf.w};
    float2 mout;
    float s_sl1 = 0.f, s_cep = 0.f;
    int np = 0;
#pragma unroll
    for (int j = 0; j < 2; ++j) {
        u32 vb = (u32)(bk[j] >> 6);
        float bv = __uint_as_float(vb);
        int o = 63 - (int)(bk[j] & 63);
        int cfv = (bv < THRESH) ? 0 : ((int)tlab[o] + 1);
        bool pos = cfv > 0;
        float4 ld = ((const float4*)loc)[gbase + j];
        float sl1 = smooth_l1_sum(ld, pr[j], tbc[o]);
        float ce = lse2(c0[j], c1[j]) - ((cfv == 0) ? c0[j] : c1[j]);
        if (pos) { s_sl1 += sl1; s_cep += ce; np++; }
        ((float*)&mout)[j] = pos ? 0.f : ce;
    }
    ((float2*)mine)[gbase >> 1] = mout;

#pragma unroll
    for (int m = 32; m; m >>= 1) {
        s_sl1 += __shfl_xor(s_sl1, m, 64);
        s_cep += __shfl_xor(s_cep, m, 64);
        np    += __shfl_xor(np, m, 64);
    }
    int lane = tid & 63, w = tid >> 6;
    if (lane == 0) { rs0[w] = s_sl1; rs1[w] = s_cep; rc[w] = np; }
    __syncthreads();               // keys final before publish
    if (tid < NO) atomicMax(&bpk[b * NO + tid], keys[tid]);   // direct global publish
    if (tid == 0) {
        float t0 = 0.f, t1 = 0.f; int t2 = 0;
        for (int i = 0; i < 4; ++i) { t0 += rs0[i]; t1 += rs1[i]; t2 += rc[i]; }
        part_sl1[b * NT1 + x] = t0;
        part_cep[b * NT1 + x] = t1;
        part_np [b * NT1 + x] = t2;
    }
}

// ---------------- K3: fix + deltas + column-per-lane radix-select top-k + finalize ------
// one block per batch, 1024 threads (16 waves). hist[256][33], column = lane&31:
// within-wave banks (bin+lane)%32 cover all 32 banks regardless of bin concentration
// (R4 failure mode); 4 passes only (R6 bisection failure mode: 31 serial rounds).
// Pass-0 histogram built in-kernel BEFORE the fix phase on pre-fix values, with <=32
// sub/add corrections (R9 structure — R11's hoist into kern1 cost more than it saved).
#define HCOL 33
__global__ __launch_bounds__(1024) void kern3(
        const float* __restrict__ loc, const float* __restrict__ conf,
        const float* __restrict__ priors, const float* __restrict__ targets,
        const u64* __restrict__ bpk, const float* __restrict__ mine,
        const float* __restrict__ part_sl1, const float* __restrict__ part_cep,
        const int* __restrict__ part_np,
        float* __restrict__ sl_tot, float* __restrict__ c_tot,
        int* __restrict__ np_tot, int* __restrict__ done_cnt,
        float* __restrict__ out)
{
#pragma clang fp contract(off)
    const int b = blockIdx.x, tid = threadIdx.x;
    const int wave = tid >> 6, lane = tid & 63;
    const int cl = lane & 31;                   // histogram column
    __shared__ __align__(16) float4 tbc[NO];
    __shared__ float tlab[NO], tas[NO];
    __shared__ u32 pp[NO];
    __shared__ u32 flags[1024];                 // 32768-bit mask of forced priors
    __shared__ int hist[256 * HCOL];            // 33 KB column-per-lane histogram
    __shared__ int total[256];
    __shared__ float rs[16];
    __shared__ int rc2[16];
    __shared__ float sh_sl1, sh_cep;
    __shared__ int sh_np, sh_k, sh_kk;
    __shared__ u32 sh_prefix;

    if (tid < NO * 5) {
        int o = tid / 5, c = tid % 5;
        float v = targets[b * NO * 5 + tid];
        if (c < 4) ((float*)&tbc[o])[c] = v; else tlab[o] = v;
    }
    flags[tid] = 0u;
    for (int i = tid; i < 256 * HCOL; i += 1024) hist[i] = 0;

    const float* mb = mine + (size_t)b * NP;
    float v[32];
#pragma unroll
    for (int q = 0; q < 8; ++q) {
        float4 t4 = ((const float4*)mb)[q * 1024 + tid];
        v[4 * q] = t4.x; v[4 * q + 1] = t4.y; v[4 * q + 2] = t4.z; v[4 * q + 3] = t4.w;
    }
    __syncthreads();
    // ---- pass-0 histogram on PRE-fix values (corrections applied in fix phase) ----
#pragma unroll 8
    for (int j = 0; j < 32; ++j)
        atomicAdd(&hist[(__float_as_uint(v[j]) >> 24) * HCOL + cl], 1);
    if (tid < NO) {
        float4 t = tbc[tid];
        tas[tid] = (t.z - t.x) * (t.w - t.y);
        u64 key = bpk[b * NO + tid];            // direct read (kernel boundary = visible)
        pp[tid] = (key >> 32) ? ~(u32)key : 0u; // all-zero row => argmax = 0
    }
    __syncthreads();
    if (tid < NO) {
        const int o = tid;
        const u32 p = pp[o];
        float dsl1 = 0.f, dcep = 0.f; int dnp = 0;
        bool last = true;
        for (int o2 = o + 1; o2 < NO; ++o2)
            if (pp[o2] == p) { last = false; break; }   // later o overwrites same prior
        if (last) {
            float4 prr = ((const float4*)priors)[p];
            float qx1 = prr.x - prr.z * 0.5f, qy1 = prr.y - prr.w * 0.5f;
            float qx2 = prr.x + prr.z * 0.5f, qy2 = prr.y + prr.w * 0.5f;
            float qab = prr.z * prr.w;
            float bv = -1.f; int bo_ = 0;       // pre-fix best truth (first-max)
            for (int o2 = 0; o2 < NO; ++o2) {
                float4 t2 = tbc[o2];
                float i2 = iou_corners(qx1, qy1, qx2, qy2, qab, t2.x, t2.y, t2.z, t2.w, tas[o2]);
                if (i2 > bv) { bv = i2; bo_ = o2; }
            }
            int cf_pre = (bv < THRESH) ? 0 : ((int)tlab[bo_] + 1);
            size_t gp = (size_t)b * NP + p;
            float4 ld = ((const float4*)loc)[gp];
            float2 c = ((const float2*)conf)[gp];
            float lse = lse2(c.x, c.y);
            int cf_new = (int)tlab[o] + 1;               // forced positive
            dsl1 = smooth_l1_sum(ld, prr, tbc[o]);
            dcep = lse - ((cf_new == 0) ? c.x : c.y);
            dnp = 1;
            if (cf_pre > 0) {                            // remove pre-fix contribution
                dsl1 -= smooth_l1_sum(ld, prr, tbc[bo_]);
                dcep -= lse - ((cf_pre == 0) ? c.x : c.y);
                dnp = 0;
            }
            // pass-0 correction: old value leaves its bin, 0.0 enters bin 0
            float oldv = mb[p];
            atomicSub(&hist[(__float_as_uint(oldv) >> 24) * HCOL + cl], 1);
            atomicAdd(&hist[cl], 1);
            atomicOr(&flags[p >> 5], 1u << (p & 31));
        }
        // batch stats: 64 kern1 partials + this lane's delta
        float a = part_sl1[b * NT1 + o] + part_sl1[b * NT1 + 32 + o] + dsl1;
        float d = part_cep[b * NT1 + o] + part_cep[b * NT1 + 32 + o] + dcep;
        int   n = part_np [b * NT1 + o] + part_np [b * NT1 + 32 + o] + dnp;
#pragma unroll
        for (int m = 16; m; m >>= 1) {
            a += __shfl_xor(a, m, 32);
            d += __shfl_xor(d, m, 32);
            n += __shfl_xor(n, m, 32);
        }
        if (o == 0) {
            sh_sl1 = a; sh_cep = d; sh_np = n;
            sh_k = min(7 * n, NP - 1); sh_kk = sh_k; sh_prefix = 0u;
        }
    }
    __syncthreads();
    // zero forced priors in-register (they become pos => mine 0)
#pragma unroll
    for (int q = 0; q < 8; ++q) {
        u32 word = flags[q * 128 + (tid >> 3)];
#pragma unroll
        for (int c = 0; c < 4; ++c)
            if ((word >> (((tid & 7) << 2) + c)) & 1u) v[4 * q + c] = 0.f;
    }
    const int k = sh_k;
    float topk = 0.f;
    if (k > 0) {
        for (int pass = 0; pass < 4; ++pass) {
            if (pass > 0) {                       // pass 0's hist was built above
                for (int i = tid; i < 256 * HCOL; i += 1024) hist[i] = 0;
                __syncthreads();
                const int shift = 24 - 8 * pass;
                const u32 pfx = sh_prefix;
#pragma unroll 8
                for (int j = 0; j < 32; ++j) {
                    u32 kb = __float_as_uint(v[j]);
                    if ((u32)(((u64)kb) >> (shift + 8)) == pfx)   // 64-bit shift: ok at 32
                        atomicAdd(&hist[((kb >> shift) & 255) * HCOL + cl], 1);
                }
                __syncthreads();
            }
            if (tid < 512) {   // reduce 32 columns/bin: 2 threads per bin, 16 each
                int bin = tid >> 1;
                const int base = bin * HCOL + (tid & 1) * 16;
                int s = 0;
#pragma unroll
                for (int i = 0; i < 16; ++i) s += hist[base + i];
                s += __shfl_xor(s, 1, 64);
                if ((tid & 1) == 0) total[bin] = s;
            }
            __syncthreads();
            if (tid < 64) {                  // suffix-scan select over 256 bins
                int4 h4 = ((const int4*)total)[tid];
                int s3 = h4.w, s2 = h4.z + s3, s1 = h4.y + s2, s0 = h4.x + s1;
                int acc = s0;
#pragma unroll
                for (int off = 1; off < 64; off <<= 1) {
                    int u = __shfl_down(acc, off, 64);
                    if (tid + off < 64) acc += u;
                }
                int excl = acc - s0;
                int kk = sh_kk;
                int cand = -1, nkk = 0;
                if (excl + s3 >= kk)      { cand = 4 * tid + 3; nkk = kk - excl; }
                else if (excl + s2 >= kk) { cand = 4 * tid + 2; nkk = kk - excl - s3; }
                else if (excl + s1 >= kk) { cand = 4 * tid + 1; nkk = kk - excl - s2; }
                else if (excl + s0 >= kk) { cand = 4 * tid + 0; nkk = kk - excl - s1; }
                int cmax = cand;
#pragma unroll
                for (int off = 1; off < 64; off <<= 1) cmax = max(cmax, __shfl_xor(cmax, off, 64));
                if (cand >= 0 && cand == cmax) {
                    sh_prefix = (sh_prefix << 8) | (u32)(cand & 255);
                    sh_kk = nkk;
                }
            }
            __syncthreads();
        }
        const u32 T = sh_prefix;                // exact k-th largest key
        const float tval = __uint_as_float(T);
        float s = 0.f; int c2 = 0;
#pragma unroll
        for (int j = 0; j < 32; ++j) {
            if (__float_as_uint(v[j]) > T) { s += v[j]; c2++; }
        }
#pragma unroll
        for (int m = 32; m; m >>= 1) {
            s  += __shfl_xor(s, m, 64);
            c2 += __shfl_xor(c2, m, 64);
        }
        if (lane == 0) { rs[wave] = s; rc2[wave] = c2; }
        __syncthreads();
        if (tid == 0) {
            float st = 0.f; int ct = 0;
            for (int i = 0; i < 16; ++i) { st += rs[i]; ct += rc2[i]; }
            topk = st + (float)(k - ct) * tval; // ties at T fill remaining slots
        }
    }
    if (tid == 0) {                            // accumulate + last-block finalize
        atomicAdd(sl_tot, sh_sl1);
        atomicAdd(c_tot, sh_cep + topk);
        atomicAdd(np_tot, sh_np);
        __threadfence();
        int d = atomicAdd(done_cnt, 1);
        if (d == NB - 1) {
            float sl = atomicAdd(sl_tot, 0.f);
            float cc = atomicAdd(c_tot, 0.f);
            int   nn = atomicAdd(np_tot, 0);
            float N = fmaxf((float)nn, 1.f);
            out[0] = sl / N;
            out[1] = cc / N;
        }
    }
}

extern "C" void kernel_launch(void* const* d_in, const int* in_sizes, int n_in,
                              void* d_out, int out_size, void* d_ws, size_t ws_size,
                              hipStream_t stream) {
    const float* loc     = (const float*)d_in[0];   // (B,P,4)
    const float* conf    = (const float*)d_in[1];   // (B,P,2)
    const float* priors  = (const float*)d_in[2];   // (P,4)
    const float* targets = (const float*)d_in[3];   // (B,O,5)
    float* out = (float*)d_out;

    char* ws = (char*)d_ws;
    float* mine      = (float*)ws;                   // 4 MB, fully written by kern1
    u64*   bpk       = (u64*)(ws + 4194304);         // 8 KB [b][o], atomicMax (zeroed)
    float* sl_tot    = (float*)(ws + 4202496);
    float* c_tot     = (float*)(ws + 4202500);
    int*   np_tot    = (int*)(ws + 4202504);
    int*   done_cnt  = (int*)(ws + 4202508);         // zeroed region ends 4202512
    float* part_sl1  = (float*)(ws + 4202624);       // [b][64] kern1 partials, fully written
    float* part_cep  = (float*)(ws + 4210816);
    int*   part_np   = (int*)(ws + 4219008);

    hipMemsetAsync(ws + 4194304, 0, 8208, stream);
    dim3 g1(NT1, NB);
    kern1<<<g1, 256, 0, stream>>>(loc, conf, priors, targets, mine, bpk,
                                  part_sl1, part_cep, part_np);
    kern3<<<NB, 1024, 0, stream>>>(loc, conf, priors, targets, bpk, mine,
                                   part_sl1, part_cep, part_np,
                                   sl_tot, c_tot, np_tot, done_cnt, out);
}